// Round 10
// baseline (189.353 us; speedup 1.0000x reference)
//
#include <hip/hip_runtime.h>
#include <hip/hip_bf16.h>
#include <stdint.h>

// CausalSelfAttention: B=4, T=2048, C=1024, H=16, D=64
#define NH 16
#define CD 1024
#define DD 64
#define TT 2048
#define BB 4
#define MR (BB*TT)   // 8192 rows

typedef float f32x4 __attribute__((ext_vector_type(4)));
typedef short s16x8 __attribute__((ext_vector_type(8)));

static __device__ __forceinline__ uint16_t f2bf(float f) {
  uint32_t u = __float_as_uint(f);
  u += 0x7FFFu + ((u >> 16) & 1u);   // RNE
  return (uint16_t)(u >> 16);
}

// ===========================================================================
// cvt5: fp32 -> bf16 for x, Wq, Wk, Wv, Wp in one launch (8 elems/thread)
// ===========================================================================
__global__ __launch_bounds__(256)
void cvt5(const float* __restrict__ x, const float* __restrict__ wq,
          const float* __restrict__ wk, const float* __restrict__ wv,
          const float* __restrict__ wp,
          uint16_t* __restrict__ xb, uint16_t* __restrict__ wqb,
          uint16_t* __restrict__ wkb, uint16_t* __restrict__ wvb,
          uint16_t* __restrict__ wpb)
{
  const int XN8 = (MR*CD)/8;   // 1048576
  const int WN8 = (CD*CD)/8;   // 131072
  int i = blockIdx.x*256 + threadIdx.x;
  const float* src; uint16_t* dst; int off;
  if (i < XN8) { src = x; dst = xb; off = i; }
  else {
    int r = i - XN8; int ws = r / WN8; off = r - ws*WN8;
    src = (ws==0)?wq:(ws==1)?wk:(ws==2)?wv:wp;
    dst = (ws==0)?wqb:(ws==1)?wkb:(ws==2)?wvb:wpb;
  }
  f32x4 a = *(const f32x4*)&src[(size_t)off*8];
  f32x4 b = *(const f32x4*)&src[(size_t)off*8 + 4];
  s16x8 o;
  o[0]=(short)f2bf(a.x); o[1]=(short)f2bf(a.y); o[2]=(short)f2bf(a.z); o[3]=(short)f2bf(a.w);
  o[4]=(short)f2bf(b.x); o[5]=(short)f2bf(b.y); o[6]=(short)f2bf(b.z); o[7]=(short)f2bf(b.w);
  *(s16x8*)&dst[(size_t)off*8] = o;
}

// ---------------------------------------------------------------------------
// shared wait/barrier macros
// ---------------------------------------------------------------------------
#define GQ_SBAR  { __builtin_amdgcn_s_barrier(); __builtin_amdgcn_sched_barrier(0); }
#define GQ_LGKM  { asm volatile("s_waitcnt lgkmcnt(0)" ::: "memory"); __builtin_amdgcn_sched_barrier(0); }
#define GQ_VM3   { asm volatile("s_waitcnt vmcnt(3)" ::: "memory"); __builtin_amdgcn_sched_barrier(0); }
#define GQ_VM6   { asm volatile("s_waitcnt vmcnt(6)" ::: "memory"); __builtin_amdgcn_sched_barrier(0); }
#define GQ_VM0   { asm volatile("s_waitcnt vmcnt(0)" ::: "memory"); __builtin_amdgcn_sched_barrier(0); }

// ===========================================================================
// gemm_qkv8m: merged QKV GEMM (round-9 proven). BM=128 x BN=256, BK=64,
// 8 waves, ONE phase per K-tile, 3 LDS buffers (144 KiB), lookahead-2,
// vmcnt(6) counted waits. Grid 768 = 3 exact residency rounds.
// ===========================================================================
__global__ __launch_bounds__(512)
void gemm_qkv8m(const uint16_t* __restrict__ xb, const uint16_t* __restrict__ wqkv,
                const float* __restrict__ bq, const float* __restrict__ bk,
                const float* __restrict__ bv,
                uint16_t* __restrict__ qo, uint16_t* __restrict__ ko,
                uint16_t* __restrict__ vo)
{
  __shared__ __align__(16) uint16_t lA[3][2][128*32];   // [buf][kh] 48 KiB
  __shared__ __align__(16) uint16_t lB[3][2][256*32];   // [buf][kh] 96 KiB

  const int tid = threadIdx.x, lane = tid & 63;
  const int g = lane >> 4, r16 = lane & 15;
  const int w = tid >> 6;                    // 0..7
  const int wr = w >> 2, wc = w & 3;         // 2M x 4N wave grid
  const int sw8 = ((g ^ ((r16 >> 1) & 3)) << 3);

  const int bid = blockIdx.x;
  const int lin = (bid & 7)*96 + (bid >> 3);   // 0..767 col-major
  const int cx = lin >> 6, my = lin & 63;
  const int rowBase = my * 128, colBase = cx * 256;
  const int z = colBase >> 10;                 // 0:q 1:k 2:v
  const bool vt = (z == 2);
  const float* bias  = (z==0) ? bq : (z==1) ? bk : bv;
  uint16_t* Out      = (z==0) ? qo : (z==1) ? ko : vo;
  const float oscale = (z==0) ? 0.125f : 1.0f;

  auto stageA = [&](int buf, int kh, int kt) {    // 1 gll (8 KB, 8 waves)
    const int row = w*16 + (lane >> 2);           // 0..127
    const int k = kt*64 + kh*32 + (((lane & 3) ^ ((row >> 1) & 3)) << 3);
    __builtin_amdgcn_global_load_lds(
      (const void*)(xb + (size_t)(rowBase + row)*CD + k),
      (void*)&lA[buf][kh][(w*16)*32], 16, 0, 0);
  };
  auto stageB = [&](int buf, int kh, int kt) {    // 2 gll (16 KB)
    #pragma unroll
    for (int c = 0; c < 2; ++c) {
      const int r0 = (c*8 + w)*16;
      const int row = r0 + (lane >> 2);
      const int k = kt*64 + kh*32 + (((lane & 3) ^ ((row >> 1) & 3)) << 3);
      __builtin_amdgcn_global_load_lds(
        (const void*)(wqkv + (size_t)(colBase + row)*CD + k),
        (void*)&lB[buf][kh][r0*32], 16, 0, 0);
    }
  };
  auto stageTile = [&](int buf, int kt) {         // 6 gll total
    stageA(buf, 0, kt); stageB(buf, 0, kt);
    stageA(buf, 1, kt); stageB(buf, 1, kt);
  };

  f32x4 acc[4][4];
  #pragma unroll
  for (int i = 0; i < 4; ++i)
    #pragma unroll
    for (int j = 0; j < 4; ++j) acc[i][j] = (f32x4){0.f,0.f,0.f,0.f};

  stageTile(0, 0);
  stageTile(1, 1);
  GQ_VM6

  int cur = 0;
  for (int t = 0; t < 16; ++t) {
    const int nxt2 = (cur + 2 >= 3) ? cur - 1 : cur + 2;
    GQ_SBAR
    s16x8 af[2][4], bf[2][4];
    #pragma unroll
    for (int kh = 0; kh < 2; ++kh) {
      #pragma unroll
      for (int i = 0; i < 4; ++i) {
        int row = wr*64 + i*16 + r16;
        af[kh][i] = *(const s16x8*)&lA[cur][kh][row*32 + sw8];
      }
      #pragma unroll
      for (int j = 0; j < 4; ++j) {
        int row = wc*64 + j*16 + r16;
        bf[kh][j] = *(const s16x8*)&lB[cur][kh][row*32 + sw8];
      }
    }
    if (t < 14) stageTile(nxt2, t + 2);
    GQ_LGKM
    __builtin_amdgcn_s_setprio(1);
    if (!vt) {
      #pragma unroll
      for (int kh = 0; kh < 2; ++kh)
        #pragma unroll
        for (int i = 0; i < 4; ++i)
          #pragma unroll
          for (int j = 0; j < 4; ++j)
            acc[i][j] = __builtin_amdgcn_mfma_f32_16x16x32_bf16(af[kh][i], bf[kh][j], acc[i][j], 0,0,0);
    } else {
      #pragma unroll
      for (int kh = 0; kh < 2; ++kh)
        #pragma unroll
        for (int i = 0; i < 4; ++i)
          #pragma unroll
          for (int j = 0; j < 4; ++j)
            acc[i][j] = __builtin_amdgcn_mfma_f32_16x16x32_bf16(bf[kh][j], af[kh][i], acc[i][j], 0,0,0);
    }
    __builtin_amdgcn_s_setprio(0);
    if (t < 14)      GQ_VM6
    else if (t == 14) GQ_VM0
    cur = (cur == 2) ? 0 : cur + 1;
  }

  if (!vt) {   // q/k: out bf16 [B,H,T,D]
    #pragma unroll
    for (int i = 0; i < 4; ++i)
      #pragma unroll
      for (int j = 0; j < 4; ++j) {
        int n = colBase + wc*64 + j*16 + r16;
        int nl = n & 1023;
        float bb = bias[nl];
        int hh = nl >> 6, d = nl & (DD-1);
        #pragma unroll
        for (int rg = 0; rg < 4; ++rg) {
          int m = rowBase + wr*64 + i*16 + g*4 + rg;
          int b = m >> 11, t2 = m & (TT-1);
          Out[(((size_t)(b*NH + hh))*TT + t2)*DD + d] = f2bf((acc[i][j][rg] + bb) * oscale);
        }
      }
  } else {     // v: swapped MFMA -> C^T; out bf16 V^T [B,H,D,T]
    #pragma unroll
    for (int i = 0; i < 4; ++i)
      #pragma unroll
      for (int j = 0; j < 4; ++j) {
        int m = rowBase + wr*64 + i*16 + r16;
        int b = m >> 11, t2 = m & (TT-1);
        #pragma unroll
        for (int rg = 0; rg < 4; ++rg) {
          int n = colBase + wc*64 + j*16 + g*4 + rg;
          int nl = n & 1023;
          float bb = bias[nl];
          int hh = nl >> 6, d = nl & (DD-1);
          Out[(((size_t)(b*NH + hh))*DD + d)*TT + t2] = f2bf(acc[i][j][rg] + bb);
        }
      }
  }
}

// ===========================================================================
// gemm_proj8: out-projection — round-7 proven config (unchanged).
// ===========================================================================
#define GP_PHASE(DB, KH, STG, VM) { \
  GQ_SBAR \
  s16x8 af[4], bf[4]; \
  _Pragma("unroll") \
  for (int i = 0; i < 4; ++i) { \
    int row = wr*64 + i*16 + r16; \
    af[i] = *(const s16x8*)&lA[DB][KH][row*32 + sw8]; \
  } \
  _Pragma("unroll") \
  for (int j = 0; j < 4; ++j) { \
    int row = wc*64 + j*16 + r16; \
    bf[j] = *(const s16x8*)&lB[DB][KH][row*32 + sw8]; \
  } \
  STG; \
  GQ_LGKM \
  __builtin_amdgcn_s_setprio(1); \
  _Pragma("unroll") \
  for (int i = 0; i < 4; ++i) \
    _Pragma("unroll") \
    for (int j = 0; j < 4; ++j) \
      acc[i][j] = __builtin_amdgcn_mfma_f32_16x16x32_bf16(af[i], bf[j], acc[i][j], 0,0,0); \
  __builtin_amdgcn_s_setprio(0); \
  VM \
}

__global__ __launch_bounds__(512)
void gemm_proj8(const uint16_t* __restrict__ yb, const uint16_t* __restrict__ wpb,
                const float* __restrict__ bias, float* __restrict__ Out)
{
  __shared__ __align__(16) uint16_t lA[2][2][128*32];
  __shared__ __align__(16) uint16_t lB[2][2][256*32];

  const int tid = threadIdx.x, lane = tid & 63;
  const int g = lane >> 4, r16 = lane & 15;
  const int w = tid >> 6;
  const int wr = w >> 2, wc = w & 3;
  const int sw8 = ((g ^ ((r16 >> 1) & 3)) << 3);

  const int bid = blockIdx.x;
  const int lin = (bid & 7)*32 + (bid >> 3);   // 0..255 col-major
  const int cx = lin >> 6, my = lin & 63;
  const int rowBase = my * 128, colBase = cx * 256;

  auto stageA = [&](int dbuf, int kh, int kt) {
    const int row = w*16 + (lane >> 2);
    const int k = kt*64 + kh*32 + (((lane & 3) ^ ((row >> 1) & 3)) << 3);
    __builtin_amdgcn_global_load_lds(
      (const void*)(yb + (size_t)(rowBase + row)*CD + k),
      (void*)&lA[dbuf][kh][(w*16)*32], 16, 0, 0);
  };
  auto stageB = [&](int dbuf, int kh, int kt) {
    #pragma unroll
    for (int c = 0; c < 2; ++c) {
      const int r0 = (c*8 + w)*16;
      const int row = r0 + (lane >> 2);
      const int k = kt*64 + kh*32 + (((lane & 3) ^ ((row >> 1) & 3)) << 3);
      __builtin_amdgcn_global_load_lds(
        (const void*)(wpb + (size_t)(colBase + row)*CD + k),
        (void*)&lB[dbuf][kh][r0*32], 16, 0, 0);
    }
  };

  f32x4 acc[4][4];
  #pragma unroll
  for (int i = 0; i < 4; ++i)
    #pragma unroll
    for (int j = 0; j < 4; ++j) acc[i][j] = (f32x4){0.f,0.f,0.f,0.f};

  stageA(0, 0, 0); stageB(0, 0, 0);
  stageA(0, 1, 0); stageB(0, 1, 0);
  GQ_VM3

  for (int t = 0; t < 8; ++t) {
    const int kt1 = 2*t + 1, kt2 = 2*t + 2;
    const bool last = (t == 7);
    GP_PHASE(0, 0, { stageA(1,0,kt1); stageB(1,0,kt1); }, GQ_VM3)
    GP_PHASE(0, 1, { stageA(1,1,kt1); stageB(1,1,kt1); }, GQ_VM3)
    GP_PHASE(1, 0, if (!last) { stageA(0,0,kt2); stageB(0,0,kt2); },
                   if (!last) GQ_VM3 else GQ_VM0)
    GP_PHASE(1, 1, if (!last) { stageA(0,1,kt2); stageB(0,1,kt2); },
                   if (!last) GQ_VM3)
  }

  #pragma unroll
  for (int i = 0; i < 4; ++i)
    #pragma unroll
    for (int j = 0; j < 4; ++j) {
      int n = colBase + wc*64 + j*16 + r16;
      float bb = bias[n];
      #pragma unroll
      for (int rg = 0; rg < 4; ++rg) {
        int m = rowBase + wr*64 + i*16 + g*4 + rg;
        Out[(size_t)m*CD + n] = acc[i][j][rg] + bb;
      }
    }
}

// ===========================================================================
// attn64p: QBLK=64 per block (4 waves x 16 q-rows), grid 1024 paired
// (a, 31-a) -> 33 KV-tiles/block uniform. LDS 40 KiB -> 4 blocks/CU
// (16 waves/CU: doubles the wave pool that hides the softmax VALU chain).
// Static-max softmax (P = exp(S), q pre-scaled 1/8), MFMA-ones rowsum,
// K + V^T via global_load_lds (pre-swizzled src), double-buffered,
// one __syncthreads per tile. XCD decode: 8 (b,h) groups x 16 pairs / XCD.
// ===========================================================================
__global__ __launch_bounds__(256)
void attn64p(const uint16_t* __restrict__ qg, const uint16_t* __restrict__ kg,
             const uint16_t* __restrict__ vtg, uint16_t* __restrict__ yg)
{
  __shared__ __align__(16) uint16_t lK[2][64*64];
  __shared__ __align__(16) uint16_t lV[2][64*64];
  __shared__ __align__(16) uint16_t lP[4][16*64];   // 40 KiB total

  const int tid = threadIdx.x, lane = tid & 63;
  const int g = lane >> 4, r16 = lane & 15;
  const int w = tid >> 6;
  const int id  = blockIdx.x;                // 0..1023
  const int xcd = id & 7, idx = id >> 3;     // idx 0..127
  const int gid = xcd + 8*(idx >> 4);        // 0..63 = b*16+h
  const int xq  = idx & 15;                  // 0..15 = q-pair index
  const int h = gid & 15, b = gid >> 4;
  const size_t kbase = ((size_t)(b*NH + h)) * TT * DD;   // q/k base
  const size_t vbase = ((size_t)(b*NH + h)) * DD * TT;   // v^T base

  const short oe = (r16 == 0) ? (short)0x3F80 : (short)0;   // bf16 1.0 / 0
  const s16x8 onesf = {oe,oe,oe,oe,oe,oe,oe,oe};

  auto stage = [&](int cur, int jt) {
    #pragma unroll
    for (int c = 0; c < 2; ++c) {
      int row = w*16 + c*8 + (lane >> 3);
      int sc  = (lane & 7) ^ (row & 7);
      __builtin_amdgcn_global_load_lds(
        (const void*)(kg + kbase + (size_t)(jt*64 + row)*DD + sc*8),
        (void*)&lK[cur][(w*16 + c*8)*64], 16, 0, 0);
      __builtin_amdgcn_global_load_lds(
        (const void*)(vtg + vbase + (size_t)row*TT + jt*64 + sc*8),
        (void*)&lV[cur][(w*16 + c*8)*64], 16, 0, 0);
    }
  };

  for (int ph = 0; ph < 2; ++ph) {
    const int qbi = ph ? 31 - xq : xq;       // 64-row q-tile index 0..31
    const int qrow0 = qbi*64 + w*16;         // this wave's 16 q-rows

    s16x8 qf[2];
    #pragma unroll
    for (int ks = 0; ks < 2; ++ks)
      qf[ks] = *(const s16x8*)&qg[kbase + (size_t)(qrow0 + r16)*DD + ks*32 + g*8];

    f32x4 accY[4];
    f32x4 accL;
    #pragma unroll
    for (int i = 0; i < 4; ++i) accY[i] = (f32x4){0.f,0.f,0.f,0.f};
    accL = (f32x4){0.f,0.f,0.f,0.f};

    const int njt = qbi + 1;
    __syncthreads();          // phase boundary: prior phase's LDS reads done
    stage(0, 0);
    int cur = 0;
    for (int jt = 0; jt < njt; ++jt) {
      __syncthreads();                          // buf[cur] ready
      if (jt + 1 < njt) stage(cur ^ 1, jt + 1); // overlap next-tile loads
      // all waves active for jt < qbi; diag tile masked
      f32x4 sacc[4];
      #pragma unroll
      for (int sb = 0; sb < 4; ++sb) sacc[sb] = (f32x4){0.f,0.f,0.f,0.f};
      __builtin_amdgcn_s_setprio(1);
      #pragma unroll
      for (int sb = 0; sb < 4; ++sb)
        #pragma unroll
        for (int ks = 0; ks < 2; ++ks) {
          int row = sb*16 + r16;
          int ch = (ks*4 + g) ^ (row & 7);
          s16x8 kf = *(const s16x8*)&lK[cur][row*64 + ch*8];
          sacc[sb] = __builtin_amdgcn_mfma_f32_16x16x32_bf16(qf[ks], kf, sacc[sb], 0,0,0);
        }
      __builtin_amdgcn_s_setprio(0);
      if (jt*64 + 63 > qrow0) {               // diagonal-crossing: mask
        #pragma unroll
        for (int sb = 0; sb < 4; ++sb)
          #pragma unroll
          for (int rg = 0; rg < 4; ++rg)
            if (jt*64 + sb*16 + r16 > qrow0 + g*4 + rg) sacc[sb][rg] = -1.0e30f;
      }
      // P = exp(S), packed cvt to bf16, -> per-wave LDS (XOR swizzle)
      #pragma unroll
      for (int sb = 0; sb < 4; ++sb) {
        int c = sb*16 + r16;
        #pragma unroll
        for (int rgp = 0; rgp < 2; ++rgp) {
          float2 fp;
          fp.x = __expf(sacc[sb][2*rgp]);
          fp.y = __expf(sacc[sb][2*rgp + 1]);
          __hip_bfloat162 h2 = __float22bfloat162_rn(fp);
          uint32_t u = *(uint32_t*)&h2;
          int row0 = g*4 + 2*rgp;
          lP[w][row0*64 + (((c>>3) ^ (row0&7))<<3) + (c&7)] = (uint16_t)(u & 0xffffu);
          int row1 = row0 + 1;
          lP[w][row1*64 + (((c>>3) ^ (row1&7))<<3) + (c&7)] = (uint16_t)(u >> 16);
        }
      }
      s16x8 pf[2];
      #pragma unroll
      for (int ks = 0; ks < 2; ++ks)
        pf[ks] = *(const s16x8*)&lP[w][r16*64 + (((ks*4 + g) ^ (r16&7))<<3)];
      __builtin_amdgcn_s_setprio(1);
      #pragma unroll
      for (int ks = 0; ks < 2; ++ks) {
        #pragma unroll
        for (int dblk = 0; dblk < 4; ++dblk) {
          int row = dblk*16 + r16;
          int ch = (ks*4 + g) ^ (row & 7);
          s16x8 vf = *(const s16x8*)&lV[cur][row*64 + ch*8];
          accY[dblk] = __builtin_amdgcn_mfma_f32_16x16x32_bf16(pf[ks], vf, accY[dblk], 0,0,0);
        }
        accL = __builtin_amdgcn_mfma_f32_16x16x32_bf16(pf[ks], onesf, accL, 0,0,0);
      }
      __builtin_amdgcn_s_setprio(0);
      cur ^= 1;
    }

    // finalize: l lives in lanes r16==0 (col 0); broadcast within g-group
    float ls[4];
    #pragma unroll
    for (int rg = 0; rg < 4; ++rg)
      ls[rg] = __shfl(accL[rg], lane & 48);
    #pragma unroll
    for (int dblk = 0; dblk < 4; ++dblk) {
      int d = dblk*16 + r16;
      #pragma unroll
      for (int rg = 0; rg < 4; ++rg) {
        int t = qrow0 + g*4 + rg;
        yg[((size_t)b*TT + t)*CD + h*DD + d] = f2bf(accY[dblk][rg] / ls[rg]);
      }
    }
  }
}

// ===========================================================================
// Fallback reg-staged GEMM (small ws). OM 0: fp32 A -> bf16 [B,H,T,D] (scaled);
// OM 1: bf16 A -> fp32; OM 2: fp32 A -> V^T bf16
// ===========================================================================
template<int OM>
__global__ __launch_bounds__(256)
void gemm128o(const void* __restrict__ Aptr, const float* __restrict__ W,
              const float* __restrict__ bias, void* __restrict__ Out, float oscale)
{
  __shared__ __align__(16) uint16_t lA[128*40];
  __shared__ __align__(16) uint16_t lB[128*40];
  const int tid = threadIdx.x, lane = tid & 63;
  const int g = lane >> 4, r16 = lane & 15;
  const int w = tid >> 6, wr = w >> 1, wc = w & 1;
  const int rowBase = blockIdx.y * 128, colBase = blockIdx.x * 128;

  f32x4 acc[4][4];
  #pragma unroll
  for (int i = 0; i < 4; ++i)
    #pragma unroll
    for (int j = 0; j < 4; ++j) acc[i][j] = (f32x4){0.f,0.f,0.f,0.f};

  for (int k0 = 0; k0 < CD; k0 += 32) {
    if (OM != 1) {
      const float* A = (const float*)Aptr;
      #pragma unroll
      for (int p = 0; p < 4; ++p) {
        int rr = p*32 + (tid >> 3), kc = (tid & 7)*4;
        f32x4 v = *(const f32x4*)&A[(size_t)(rowBase + rr)*CD + k0 + kc];
        uint64_t pk = (uint64_t)f2bf(v.x) | ((uint64_t)f2bf(v.y)<<16)
                    | ((uint64_t)f2bf(v.z)<<32) | ((uint64_t)f2bf(v.w)<<48);
        *(uint64_t*)&lA[rr*40 + kc] = pk;
      }
    } else {
      const uint16_t* A = (const uint16_t*)Aptr;
      #pragma unroll
      for (int p = 0; p < 2; ++p) {
        int rr = p*64 + (tid >> 2), kc = (tid & 3)*8;
        *(s16x8*)&lA[rr*40 + kc] = *(const s16x8*)&A[(size_t)(rowBase + rr)*CD + k0 + kc];
      }
    }
    #pragma unroll
    for (int p = 0; p < 4; ++p) {
      int rr = p*32 + (tid >> 3), kc = (tid & 7)*4;
      f32x4 v = *(const f32x4*)&W[(size_t)(colBase + rr)*CD + k0 + kc];
      uint64_t pk = (uint64_t)f2bf(v.x) | ((uint64_t)f2bf(v.y)<<16)
                  | ((uint64_t)f2bf(v.z)<<32) | ((uint64_t)f2bf(v.w)<<48);
      *(uint64_t*)&lB[rr*40 + kc] = pk;
    }
    __syncthreads();
    s16x8 af[4], bfr[4];
    #pragma unroll
    for (int i = 0; i < 4; ++i) {
      af[i]  = *(const s16x8*)&lA[(wr*64 + i*16 + r16)*40 + g*8];
      bfr[i] = *(const s16x8*)&lB[(wc*64 + i*16 + r16)*40 + g*8];
    }
    if (OM != 2) {
      #pragma unroll
      for (int i = 0; i < 4; ++i)
        #pragma unroll
        for (int j = 0; j < 4; ++j)
          acc[i][j] = __builtin_amdgcn_mfma_f32_16x16x32_bf16(af[i], bfr[j], acc[i][j], 0,0,0);
    } else {
      #pragma unroll
      for (int i = 0; i < 4; ++i)
        #pragma unroll
        for (int j = 0; j < 4; ++j)
          acc[i][j] = __builtin_amdgcn_mfma_f32_16x16x32_bf16(bfr[j], af[i], acc[i][j], 0,0,0);
    }
    __syncthreads();
  }

  #pragma unroll
  for (int i = 0; i < 4; ++i)
    #pragma unroll
    for (int j = 0; j < 4; ++j) {
      if (OM == 0) {
        int n = colBase + wc*64 + j*16 + r16;
        float bb = bias[n];
        int hh = n >> 6, d = n & (DD-1);
        #pragma unroll
        for (int rg = 0; rg < 4; ++rg) {
          int m = rowBase + wr*64 + i*16 + g*4 + rg;
          int b = m >> 11, t = m & (TT-1);
          ((uint16_t*)Out)[(((size_t)(b*NH + hh))*TT + t)*DD + d] = f2bf((acc[i][j][rg] + bb) * oscale);
        }
      } else if (OM == 1) {
        int n = colBase + wc*64 + j*16 + r16;
        float bb = bias[n];
        #pragma unroll
        for (int rg = 0; rg < 4; ++rg) {
          int m = rowBase + wr*64 + i*16 + g*4 + rg;
          ((float*)Out)[(size_t)m*CD + n] = acc[i][j][rg] + bb;
        }
      } else {
        int m = rowBase + wr*64 + i*16 + r16;
        int b = m >> 11, t = m & (TT-1);
        #pragma unroll
        for (int rg = 0; rg < 4; ++rg) {
          int n = colBase + wc*64 + j*16 + g*4 + rg;
          float bb = bias[n];
          int hh = n >> 6, d = n & (DD-1);
          ((uint16_t*)Out)[(((size_t)(b*NH + hh))*DD + d)*TT + t] = f2bf(acc[i][j][rg] + bb);
        }
      }
    }
}

// ===========================================================================
extern "C" void kernel_launch(void* const* d_in, const int* in_sizes, int n_in,
                              void* d_out, int out_size, void* d_ws, size_t ws_size,
                              hipStream_t stream)
{
  const float* x  = (const float*)d_in[0];
  const float* Wk = (const float*)d_in[1];
  const float* bk = (const float*)d_in[2];
  const float* Wq = (const float*)d_in[3];
  const float* bq = (const float*)d_in[4];
  const float* Wv = (const float*)d_in[5];
  const float* bv = (const float*)d_in[6];
  const float* Wp = (const float*)d_in[7];
  const float* bp = (const float*)d_in[8];
  float* out = (float*)d_out;

  const size_t elems = (size_t)MR * CD;      // 8388608
  const size_t welems = (size_t)CD * CD;     // 1048576

  if (ws_size >= 76ull*1024*1024) {
    uint16_t* xbf = (uint16_t*)d_ws;
    uint16_t* wqb = xbf + elems;             // wq|wk|wv contiguous = [3072][1024]
    uint16_t* wkb = wqb + welems;
    uint16_t* wvb = wkb + welems;
    uint16_t* wpb = wvb + welems;
    uint16_t* q_ws = wpb + welems;
    uint16_t* k_ws = q_ws + elems;
    uint16_t* v_ws = k_ws + elems;
    uint16_t* y_ws = xbf;                    // alias: x dead after QKV GEMM

    cvt5<<<6144, 256, 0, stream>>>(x, Wq, Wk, Wv, Wp, xbf, wqb, wkb, wvb, wpb);
    gemm_qkv8m<<<768, 512, 0, stream>>>(xbf, wqb, bq, bk, bv, q_ws, k_ws, v_ws);
    attn64p<<<1024, 256, 0, stream>>>(q_ws, k_ws, v_ws, y_ws);
    gemm_proj8<<<256, 512, 0, stream>>>(y_ws, wpb, bp, out);
  } else {
    uint16_t* q_ws = (uint16_t*)d_ws;
    uint16_t* k_ws = q_ws + elems;
    uint16_t* v_ws = k_ws + elems;
    uint16_t* y_ws = v_ws + elems;
    dim3 gg(CD/128, MR/128);
    gemm128o<0><<<gg, 256, 0, stream>>>(x, Wq, bq, q_ws, 0.125f);
    gemm128o<0><<<gg, 256, 0, stream>>>(x, Wk, bk, k_ws, 1.0f);
    gemm128o<2><<<gg, 256, 0, stream>>>(x, Wv, bv, v_ws, 1.0f);
    attn64p<<<1024, 256, 0, stream>>>(q_ws, k_ws, v_ws, y_ws);
    gemm128o<1><<<gg, 256, 0, stream>>>(y_ws, Wp, bp, out, 1.0f);
  }
}

// Round 11
// 170.704 us; speedup vs baseline: 1.1092x; 1.1092x over previous
//
#include <hip/hip_runtime.h>
#include <hip/hip_bf16.h>
#include <stdint.h>

// CausalSelfAttention: B=4, T=2048, C=1024, H=16, D=64
#define NH 16
#define CD 1024
#define DD 64
#define TT 2048
#define BB 4
#define MR (BB*TT)   // 8192 rows

// q-projection scale: 1/sqrt(64) * log2(e)  (exp2 fold — attn uses v_exp_f32 = 2^x)
#define QSCALE (0.125f * 1.44269504f)

typedef float f32x4 __attribute__((ext_vector_type(4)));
typedef short s16x8 __attribute__((ext_vector_type(8)));

static __device__ __forceinline__ uint16_t f2bf(float f) {
  uint32_t u = __float_as_uint(f);
  u += 0x7FFFu + ((u >> 16) & 1u);   // RNE
  return (uint16_t)(u >> 16);
}

// ===========================================================================
// cvt5: fp32 -> bf16 for x, Wq, Wk, Wv, Wp in one launch (8 elems/thread)
// ===========================================================================
__global__ __launch_bounds__(256)
void cvt5(const float* __restrict__ x, const float* __restrict__ wq,
          const float* __restrict__ wk, const float* __restrict__ wv,
          const float* __restrict__ wp,
          uint16_t* __restrict__ xb, uint16_t* __restrict__ wqb,
          uint16_t* __restrict__ wkb, uint16_t* __restrict__ wvb,
          uint16_t* __restrict__ wpb)
{
  const int XN8 = (MR*CD)/8;   // 1048576
  const int WN8 = (CD*CD)/8;   // 131072
  int i = blockIdx.x*256 + threadIdx.x;
  const float* src; uint16_t* dst; int off;
  if (i < XN8) { src = x; dst = xb; off = i; }
  else {
    int r = i - XN8; int ws = r / WN8; off = r - ws*WN8;
    src = (ws==0)?wq:(ws==1)?wk:(ws==2)?wv:wp;
    dst = (ws==0)?wqb:(ws==1)?wkb:(ws==2)?wvb:wpb;
  }
  f32x4 a = *(const f32x4*)&src[(size_t)off*8];
  f32x4 b = *(const f32x4*)&src[(size_t)off*8 + 4];
  s16x8 o;
  o[0]=(short)f2bf(a.x); o[1]=(short)f2bf(a.y); o[2]=(short)f2bf(a.z); o[3]=(short)f2bf(a.w);
  o[4]=(short)f2bf(b.x); o[5]=(short)f2bf(b.y); o[6]=(short)f2bf(b.z); o[7]=(short)f2bf(b.w);
  *(s16x8*)&dst[(size_t)off*8] = o;
}

// ---------------------------------------------------------------------------
// shared wait/barrier macros
// ---------------------------------------------------------------------------
#define GQ_SBAR  { __builtin_amdgcn_s_barrier(); __builtin_amdgcn_sched_barrier(0); }
#define GQ_LGKM  { asm volatile("s_waitcnt lgkmcnt(0)" ::: "memory"); __builtin_amdgcn_sched_barrier(0); }
#define GQ_VM6   { asm volatile("s_waitcnt vmcnt(6)" ::: "memory"); __builtin_amdgcn_sched_barrier(0); }
#define GQ_VM0   { asm volatile("s_waitcnt vmcnt(0)" ::: "memory"); __builtin_amdgcn_sched_barrier(0); }

// ===========================================================================
// gemm_qkv8m: merged QKV GEMM (round-9 proven). BM=128 x BN=256, BK=64,
// 8 waves, ONE phase per K-tile, 3 LDS buffers (144 KiB), lookahead-2,
// vmcnt(6) counted waits. Grid 768 = 3 exact residency rounds.
// ===========================================================================
__global__ __launch_bounds__(512)
void gemm_qkv8m(const uint16_t* __restrict__ xb, const uint16_t* __restrict__ wqkv,
                const float* __restrict__ bq, const float* __restrict__ bk,
                const float* __restrict__ bv,
                uint16_t* __restrict__ qo, uint16_t* __restrict__ ko,
                uint16_t* __restrict__ vo)
{
  __shared__ __align__(16) uint16_t lA[3][2][128*32];   // [buf][kh] 48 KiB
  __shared__ __align__(16) uint16_t lB[3][2][256*32];   // [buf][kh] 96 KiB

  const int tid = threadIdx.x, lane = tid & 63;
  const int g = lane >> 4, r16 = lane & 15;
  const int w = tid >> 6;                    // 0..7
  const int wr = w >> 2, wc = w & 3;         // 2M x 4N wave grid
  const int sw8 = ((g ^ ((r16 >> 1) & 3)) << 3);

  const int bid = blockIdx.x;
  const int lin = (bid & 7)*96 + (bid >> 3);   // 0..767 col-major
  const int cx = lin >> 6, my = lin & 63;
  const int rowBase = my * 128, colBase = cx * 256;
  const int z = colBase >> 10;                 // 0:q 1:k 2:v
  const bool vt = (z == 2);
  const float* bias  = (z==0) ? bq : (z==1) ? bk : bv;
  uint16_t* Out      = (z==0) ? qo : (z==1) ? ko : vo;
  const float oscale = (z==0) ? QSCALE : 1.0f;

  auto stageA = [&](int buf, int kh, int kt) {    // 1 gll (8 KB, 8 waves)
    const int row = w*16 + (lane >> 2);           // 0..127
    const int k = kt*64 + kh*32 + (((lane & 3) ^ ((row >> 1) & 3)) << 3);
    __builtin_amdgcn_global_load_lds(
      (const void*)(xb + (size_t)(rowBase + row)*CD + k),
      (void*)&lA[buf][kh][(w*16)*32], 16, 0, 0);
  };
  auto stageB = [&](int buf, int kh, int kt) {    // 2 gll (16 KB)
    #pragma unroll
    for (int c = 0; c < 2; ++c) {
      const int r0 = (c*8 + w)*16;
      const int row = r0 + (lane >> 2);
      const int k = kt*64 + kh*32 + (((lane & 3) ^ ((row >> 1) & 3)) << 3);
      __builtin_amdgcn_global_load_lds(
        (const void*)(wqkv + (size_t)(colBase + row)*CD + k),
        (void*)&lB[buf][kh][r0*32], 16, 0, 0);
    }
  };
  auto stageTile = [&](int buf, int kt) {         // 6 gll total
    stageA(buf, 0, kt); stageB(buf, 0, kt);
    stageA(buf, 1, kt); stageB(buf, 1, kt);
  };

  f32x4 acc[4][4];
  #pragma unroll
  for (int i = 0; i < 4; ++i)
    #pragma unroll
    for (int j = 0; j < 4; ++j) acc[i][j] = (f32x4){0.f,0.f,0.f,0.f};

  stageTile(0, 0);
  stageTile(1, 1);
  GQ_VM6

  int cur = 0;
  for (int t = 0; t < 16; ++t) {
    const int nxt2 = (cur + 2 >= 3) ? cur - 1 : cur + 2;
    GQ_SBAR
    s16x8 af[2][4], bf[2][4];
    #pragma unroll
    for (int kh = 0; kh < 2; ++kh) {
      #pragma unroll
      for (int i = 0; i < 4; ++i) {
        int row = wr*64 + i*16 + r16;
        af[kh][i] = *(const s16x8*)&lA[cur][kh][row*32 + sw8];
      }
      #pragma unroll
      for (int j = 0; j < 4; ++j) {
        int row = wc*64 + j*16 + r16;
        bf[kh][j] = *(const s16x8*)&lB[cur][kh][row*32 + sw8];
      }
    }
    if (t < 14) stageTile(nxt2, t + 2);
    GQ_LGKM
    __builtin_amdgcn_s_setprio(1);
    if (!vt) {
      #pragma unroll
      for (int kh = 0; kh < 2; ++kh)
        #pragma unroll
        for (int i = 0; i < 4; ++i)
          #pragma unroll
          for (int j = 0; j < 4; ++j)
            acc[i][j] = __builtin_amdgcn_mfma_f32_16x16x32_bf16(af[kh][i], bf[kh][j], acc[i][j], 0,0,0);
    } else {
      #pragma unroll
      for (int kh = 0; kh < 2; ++kh)
        #pragma unroll
        for (int i = 0; i < 4; ++i)
          #pragma unroll
          for (int j = 0; j < 4; ++j)
            acc[i][j] = __builtin_amdgcn_mfma_f32_16x16x32_bf16(bf[kh][j], af[kh][i], acc[i][j], 0,0,0);
    }
    __builtin_amdgcn_s_setprio(0);
    if (t < 14)      GQ_VM6
    else if (t == 14) GQ_VM0
    cur = (cur == 2) ? 0 : cur + 1;
  }

  if (!vt) {   // q/k: out bf16 [B,H,T,D]
    #pragma unroll
    for (int i = 0; i < 4; ++i)
      #pragma unroll
      for (int j = 0; j < 4; ++j) {
        int n = colBase + wc*64 + j*16 + r16;
        int nl = n & 1023;
        float bb = bias[nl];
        int hh = nl >> 6, d = nl & (DD-1);
        #pragma unroll
        for (int rg = 0; rg < 4; ++rg) {
          int m = rowBase + wr*64 + i*16 + g*4 + rg;
          int b = m >> 11, t2 = m & (TT-1);
          Out[(((size_t)(b*NH + hh))*TT + t2)*DD + d] = f2bf((acc[i][j][rg] + bb) * oscale);
        }
      }
  } else {     // v: swapped MFMA -> C^T; out bf16 V^T [B,H,D,T]
    #pragma unroll
    for (int i = 0; i < 4; ++i)
      #pragma unroll
      for (int j = 0; j < 4; ++j) {
        int m = rowBase + wr*64 + i*16 + r16;
        int b = m >> 11, t2 = m & (TT-1);
        #pragma unroll
        for (int rg = 0; rg < 4; ++rg) {
          int n = colBase + wc*64 + j*16 + g*4 + rg;
          int nl = n & 1023;
          float bb = bias[nl];
          int hh = nl >> 6, d = nl & (DD-1);
          Out[(((size_t)(b*NH + hh))*DD + d)*TT + t2] = f2bf(acc[i][j][rg] + bb);
        }
      }
  }
}

// ===========================================================================
// gemm_proj8m: out-projection ported to the merged-phase template (qkv8m
// structure: one phase per K-tile, 3 LDS buffers, lookahead-2, vmcnt(6)).
// Grid 256 = exactly one residency round (64 row-tiles x 4 col-tiles).
// ===========================================================================
__global__ __launch_bounds__(512)
void gemm_proj8m(const uint16_t* __restrict__ yb, const uint16_t* __restrict__ wpb,
                 const float* __restrict__ bias, float* __restrict__ Out)
{
  __shared__ __align__(16) uint16_t lA[3][2][128*32];
  __shared__ __align__(16) uint16_t lB[3][2][256*32];

  const int tid = threadIdx.x, lane = tid & 63;
  const int g = lane >> 4, r16 = lane & 15;
  const int w = tid >> 6;
  const int wr = w >> 2, wc = w & 3;
  const int sw8 = ((g ^ ((r16 >> 1) & 3)) << 3);

  const int bid = blockIdx.x;
  const int lin = (bid & 7)*32 + (bid >> 3);   // 0..255 col-major
  const int cx = lin >> 6, my = lin & 63;
  const int rowBase = my * 128, colBase = cx * 256;

  auto stageA = [&](int buf, int kh, int kt) {
    const int row = w*16 + (lane >> 2);
    const int k = kt*64 + kh*32 + (((lane & 3) ^ ((row >> 1) & 3)) << 3);
    __builtin_amdgcn_global_load_lds(
      (const void*)(yb + (size_t)(rowBase + row)*CD + k),
      (void*)&lA[buf][kh][(w*16)*32], 16, 0, 0);
  };
  auto stageB = [&](int buf, int kh, int kt) {
    #pragma unroll
    for (int c = 0; c < 2; ++c) {
      const int r0 = (c*8 + w)*16;
      const int row = r0 + (lane >> 2);
      const int k = kt*64 + kh*32 + (((lane & 3) ^ ((row >> 1) & 3)) << 3);
      __builtin_amdgcn_global_load_lds(
        (const void*)(wpb + (size_t)(colBase + row)*CD + k),
        (void*)&lB[buf][kh][r0*32], 16, 0, 0);
    }
  };
  auto stageTile = [&](int buf, int kt) {
    stageA(buf, 0, kt); stageB(buf, 0, kt);
    stageA(buf, 1, kt); stageB(buf, 1, kt);
  };

  f32x4 acc[4][4];
  #pragma unroll
  for (int i = 0; i < 4; ++i)
    #pragma unroll
    for (int j = 0; j < 4; ++j) acc[i][j] = (f32x4){0.f,0.f,0.f,0.f};

  stageTile(0, 0);
  stageTile(1, 1);
  GQ_VM6

  int cur = 0;
  for (int t = 0; t < 16; ++t) {
    const int nxt2 = (cur + 2 >= 3) ? cur - 1 : cur + 2;
    GQ_SBAR
    s16x8 af[2][4], bf[2][4];
    #pragma unroll
    for (int kh = 0; kh < 2; ++kh) {
      #pragma unroll
      for (int i = 0; i < 4; ++i) {
        int row = wr*64 + i*16 + r16;
        af[kh][i] = *(const s16x8*)&lA[cur][kh][row*32 + sw8];
      }
      #pragma unroll
      for (int j = 0; j < 4; ++j) {
        int row = wc*64 + j*16 + r16;
        bf[kh][j] = *(const s16x8*)&lB[cur][kh][row*32 + sw8];
      }
    }
    if (t < 14) stageTile(nxt2, t + 2);
    GQ_LGKM
    __builtin_amdgcn_s_setprio(1);
    #pragma unroll
    for (int kh = 0; kh < 2; ++kh)
      #pragma unroll
      for (int i = 0; i < 4; ++i)
        #pragma unroll
        for (int j = 0; j < 4; ++j)
          acc[i][j] = __builtin_amdgcn_mfma_f32_16x16x32_bf16(af[kh][i], bf[kh][j], acc[i][j], 0,0,0);
    __builtin_amdgcn_s_setprio(0);
    if (t < 14)      GQ_VM6
    else if (t == 14) GQ_VM0
    cur = (cur == 2) ? 0 : cur + 1;
  }

  #pragma unroll
  for (int i = 0; i < 4; ++i)
    #pragma unroll
    for (int j = 0; j < 4; ++j) {
      int n = colBase + wc*64 + j*16 + r16;
      float bb = bias[n];
      #pragma unroll
      for (int rg = 0; rg < 4; ++rg) {
        int m = rowBase + wr*64 + i*16 + g*4 + rg;
        Out[(size_t)m*CD + n] = acc[i][j][rg] + bb;
      }
    }
}

// ===========================================================================
// attn128s: static-max softmax flash attention (round-9 proven config;
// only change: q is pre-scaled by log2e so P = 2^S via raw v_exp_f32 —
// deletes one v_mul per P-element from the softmax VALU chain).
// ===========================================================================
__global__ __launch_bounds__(256)
void attn128s(const uint16_t* __restrict__ qg, const uint16_t* __restrict__ kg,
              const uint16_t* __restrict__ vtg, uint16_t* __restrict__ yg)
{
  __shared__ __align__(16) uint16_t lK[2][64*64];
  __shared__ __align__(16) uint16_t lV[2][64*64];
  __shared__ __align__(16) uint16_t lP[4][16*64];   // 40 KiB total

  const int tid = threadIdx.x, lane = tid & 63;
  const int g = lane >> 4, r16 = lane & 15;
  const int w = tid >> 6;
  const int id  = blockIdx.x;
  const int xcd = id & 7, idx = id >> 3;
  const int gid = xcd + 8*(idx >> 3);      // 0..63 = b*16+h
  const int xq  = idx & 7;                 // 0..7  = q-pair index
  const int h = gid & 15, b = gid >> 4;
  const size_t kbase = ((size_t)(b*NH + h)) * TT * DD;   // q/k base
  const size_t vbase = ((size_t)(b*NH + h)) * DD * TT;   // v^T base

  const short oe = (r16 == 0) ? (short)0x3F80 : (short)0;   // bf16 1.0 / 0
  const s16x8 onesf = {oe,oe,oe,oe,oe,oe,oe,oe};

  auto stage = [&](int cur, int jt) {
    #pragma unroll
    for (int c = 0; c < 2; ++c) {
      int row = w*16 + c*8 + (lane >> 3);
      int sc  = (lane & 7) ^ (row & 7);
      __builtin_amdgcn_global_load_lds(
        (const void*)(kg + kbase + (size_t)(jt*64 + row)*DD + sc*8),
        (void*)&lK[cur][(w*16 + c*8)*64], 16, 0, 0);
      __builtin_amdgcn_global_load_lds(
        (const void*)(vtg + vbase + (size_t)row*TT + jt*64 + sc*8),
        (void*)&lV[cur][(w*16 + c*8)*64], 16, 0, 0);
    }
  };

  for (int ph = 0; ph < 2; ++ph) {
    const int qbi = ph ? 15 - xq : xq;
    const int qrow0 = qbi*128 + w*32;

    s16x8 qf[2][2];
    #pragma unroll
    for (int rb = 0; rb < 2; ++rb)
      #pragma unroll
      for (int ks = 0; ks < 2; ++ks)
        qf[rb][ks] = *(const s16x8*)&qg[kbase + (size_t)(qrow0 + rb*16 + r16)*DD + ks*32 + g*8];

    f32x4 accY[2][4];
    f32x4 accL[2];
    #pragma unroll
    for (int rb = 0; rb < 2; ++rb) {
      #pragma unroll
      for (int i = 0; i < 4; ++i) accY[rb][i] = (f32x4){0.f,0.f,0.f,0.f};
      accL[rb] = (f32x4){0.f,0.f,0.f,0.f};
    }

    const int njt = 2*qbi + 2;
    __syncthreads();          // phase boundary: prior phase's LDS reads done
    stage(0, 0);
    int cur = 0;
    for (int jt = 0; jt < njt; ++jt) {
      __syncthreads();                          // buf[cur] ready
      if (jt + 1 < njt) stage(cur ^ 1, jt + 1); // overlap next-tile loads
      if (jt*64 <= qrow0 + 31) {
        f32x4 sacc[2][4];
        #pragma unroll
        for (int rb = 0; rb < 2; ++rb)
          #pragma unroll
          for (int sb = 0; sb < 4; ++sb) sacc[rb][sb] = (f32x4){0.f,0.f,0.f,0.f};
        __builtin_amdgcn_s_setprio(1);
        #pragma unroll
        for (int sb = 0; sb < 4; ++sb)
          #pragma unroll
          for (int ks = 0; ks < 2; ++ks) {
            int row = sb*16 + r16;
            int ch = (ks*4 + g) ^ (row & 7);
            s16x8 kf = *(const s16x8*)&lK[cur][row*64 + ch*8];
            sacc[0][sb] = __builtin_amdgcn_mfma_f32_16x16x32_bf16(qf[0][ks], kf, sacc[0][sb], 0,0,0);
            sacc[1][sb] = __builtin_amdgcn_mfma_f32_16x16x32_bf16(qf[1][ks], kf, sacc[1][sb], 0,0,0);
          }
        __builtin_amdgcn_s_setprio(0);
        s16x8 vfr[2][4];
        #pragma unroll
        for (int ks = 0; ks < 2; ++ks)
          #pragma unroll
          for (int dblk = 0; dblk < 4; ++dblk) {
            int row = dblk*16 + r16;
            int ch = (ks*4 + g) ^ (row & 7);
            vfr[ks][dblk] = *(const s16x8*)&lV[cur][row*64 + ch*8];
          }
        #pragma unroll
        for (int rb = 0; rb < 2; ++rb) {
          const int qr0b = qrow0 + rb*16;
          if (jt*64 > qr0b + 15) continue;      // rb fully masked
          if (jt*64 + 63 > qr0b) {
            #pragma unroll
            for (int sb = 0; sb < 4; ++sb)
              #pragma unroll
              for (int rg = 0; rg < 4; ++rg)
                if (jt*64 + sb*16 + r16 > qr0b + g*4 + rg) sacc[rb][sb][rg] = -1.0e30f;
          }
          // P = 2^S (q pre-scaled by log2e), packed cvt to bf16, -> LDS
          #pragma unroll
          for (int sb = 0; sb < 4; ++sb) {
            int c = sb*16 + r16;
            #pragma unroll
            for (int rgp = 0; rgp < 2; ++rgp) {
              float2 fp;
              asm("v_exp_f32 %0, %1" : "=v"(fp.x) : "v"(sacc[rb][sb][2*rgp]));
              asm("v_exp_f32 %0, %1" : "=v"(fp.y) : "v"(sacc[rb][sb][2*rgp + 1]));
              __hip_bfloat162 h2 = __float22bfloat162_rn(fp);
              uint32_t u = *(uint32_t*)&h2;
              int row0 = g*4 + 2*rgp;
              lP[w][row0*64 + (((c>>3) ^ (row0&7))<<3) + (c&7)] = (uint16_t)(u & 0xffffu);
              int row1 = row0 + 1;
              lP[w][row1*64 + (((c>>3) ^ (row1&7))<<3) + (c&7)] = (uint16_t)(u >> 16);
            }
          }
          s16x8 pf[2];
          #pragma unroll
          for (int ks = 0; ks < 2; ++ks)
            pf[ks] = *(const s16x8*)&lP[w][r16*64 + (((ks*4 + g) ^ (r16&7))<<3)];
          __builtin_amdgcn_s_setprio(1);
          #pragma unroll
          for (int ks = 0; ks < 2; ++ks) {
            #pragma unroll
            for (int dblk = 0; dblk < 4; ++dblk)
              accY[rb][dblk] = __builtin_amdgcn_mfma_f32_16x16x32_bf16(pf[ks], vfr[ks][dblk], accY[rb][dblk], 0,0,0);
            accL[rb] = __builtin_amdgcn_mfma_f32_16x16x32_bf16(pf[ks], onesf, accL[rb], 0,0,0);
          }
          __builtin_amdgcn_s_setprio(0);
        }
      }
      cur ^= 1;
    }

    #pragma unroll
    for (int rb = 0; rb < 2; ++rb) {
      float ls[4];
      #pragma unroll
      for (int rg = 0; rg < 4; ++rg)
        ls[rg] = __shfl(accL[rb][rg], lane & 48);
      #pragma unroll
      for (int dblk = 0; dblk < 4; ++dblk) {
        int d = dblk*16 + r16;
        #pragma unroll
        for (int rg = 0; rg < 4; ++rg) {
          int t = qrow0 + rb*16 + g*4 + rg;
          yg[((size_t)b*TT + t)*CD + h*DD + d] = f2bf(accY[rb][dblk][rg] / ls[rg]);
        }
      }
    }
  }
}

// ===========================================================================
// Fallback reg-staged GEMM (small ws). OM 0: fp32 A -> bf16 [B,H,T,D] (scaled);
// OM 1: bf16 A -> fp32; OM 2: fp32 A -> V^T bf16
// ===========================================================================
template<int OM>
__global__ __launch_bounds__(256)
void gemm128o(const void* __restrict__ Aptr, const float* __restrict__ W,
              const float* __restrict__ bias, void* __restrict__ Out, float oscale)
{
  __shared__ __align__(16) uint16_t lA[128*40];
  __shared__ __align__(16) uint16_t lB[128*40];
  const int tid = threadIdx.x, lane = tid & 63;
  const int g = lane >> 4, r16 = lane & 15;
  const int w = tid >> 6, wr = w >> 1, wc = w & 1;
  const int rowBase = blockIdx.y * 128, colBase = blockIdx.x * 128;

  f32x4 acc[4][4];
  #pragma unroll
  for (int i = 0; i < 4; ++i)
    #pragma unroll
    for (int j = 0; j < 4; ++j) acc[i][j] = (f32x4){0.f,0.f,0.f,0.f};

  for (int k0 = 0; k0 < CD; k0 += 32) {
    if (OM != 1) {
      const float* A = (const float*)Aptr;
      #pragma unroll
      for (int p = 0; p < 4; ++p) {
        int rr = p*32 + (tid >> 3), kc = (tid & 7)*4;
        f32x4 v = *(const f32x4*)&A[(size_t)(rowBase + rr)*CD + k0 + kc];
        uint64_t pk = (uint64_t)f2bf(v.x) | ((uint64_t)f2bf(v.y)<<16)
                    | ((uint64_t)f2bf(v.z)<<32) | ((uint64_t)f2bf(v.w)<<48);
        *(uint64_t*)&lA[rr*40 + kc] = pk;
      }
    } else {
      const uint16_t* A = (const uint16_t*)Aptr;
      #pragma unroll
      for (int p = 0; p < 2; ++p) {
        int rr = p*64 + (tid >> 2), kc = (tid & 3)*8;
        *(s16x8*)&lA[rr*40 + kc] = *(const s16x8*)&A[(size_t)(rowBase + rr)*CD + k0 + kc];
      }
    }
    #pragma unroll
    for (int p = 0; p < 4; ++p) {
      int rr = p*32 + (tid >> 3), kc = (tid & 7)*4;
      f32x4 v = *(const f32x4*)&W[(size_t)(colBase + rr)*CD + k0 + kc];
      uint64_t pk = (uint64_t)f2bf(v.x) | ((uint64_t)f2bf(v.y)<<16)
                  | ((uint64_t)f2bf(v.z)<<32) | ((uint64_t)f2bf(v.w)<<48);
      *(uint64_t*)&lB[rr*40 + kc] = pk;
    }
    __syncthreads();
    s16x8 af[4], bfr[4];
    #pragma unroll
    for (int i = 0; i < 4; ++i) {
      af[i]  = *(const s16x8*)&lA[(wr*64 + i*16 + r16)*40 + g*8];
      bfr[i] = *(const s16x8*)&lB[(wc*64 + i*16 + r16)*40 + g*8];
    }
    if (OM != 2) {
      #pragma unroll
      for (int i = 0; i < 4; ++i)
        #pragma unroll
        for (int j = 0; j < 4; ++j)
          acc[i][j] = __builtin_amdgcn_mfma_f32_16x16x32_bf16(af[i], bfr[j], acc[i][j], 0,0,0);
    } else {
      #pragma unroll
      for (int i = 0; i < 4; ++i)
        #pragma unroll
        for (int j = 0; j < 4; ++j)
          acc[i][j] = __builtin_amdgcn_mfma_f32_16x16x32_bf16(bfr[j], af[i], acc[i][j], 0,0,0);
    }
    __syncthreads();
  }

  #pragma unroll
  for (int i = 0; i < 4; ++i)
    #pragma unroll
    for (int j = 0; j < 4; ++j) {
      if (OM == 0) {
        int n = colBase + wc*64 + j*16 + r16;
        float bb = bias[n];
        int hh = n >> 6, d = n & (DD-1);
        #pragma unroll
        for (int rg = 0; rg < 4; ++rg) {
          int m = rowBase + wr*64 + i*16 + g*4 + rg;
          int b = m >> 11, t = m & (TT-1);
          ((uint16_t*)Out)[(((size_t)(b*NH + hh))*TT + t)*DD + d] = f2bf((acc[i][j][rg] + bb) * oscale);
        }
      } else if (OM == 1) {
        int n = colBase + wc*64 + j*16 + r16;
        float bb = bias[n];
        #pragma unroll
        for (int rg = 0; rg < 4; ++rg) {
          int m = rowBase + wr*64 + i*16 + g*4 + rg;
          ((float*)Out)[(size_t)m*CD + n] = acc[i][j][rg] + bb;
        }
      } else {
        int m = rowBase + wr*64 + i*16 + r16;
        int b = m >> 11, t = m & (TT-1);
        #pragma unroll
        for (int rg = 0; rg < 4; ++rg) {
          int n = colBase + wc*64 + j*16 + g*4 + rg;
          float bb = bias[n];
          int hh = n >> 6, d = n & (DD-1);
          ((uint16_t*)Out)[(((size_t)(b*NH + hh))*DD + d)*TT + t] = f2bf(acc[i][j][rg] + bb);
        }
      }
    }
}

// ===========================================================================
extern "C" void kernel_launch(void* const* d_in, const int* in_sizes, int n_in,
                              void* d_out, int out_size, void* d_ws, size_t ws_size,
                              hipStream_t stream)
{
  const float* x  = (const float*)d_in[0];
  const float* Wk = (const float*)d_in[1];
  const float* bk = (const float*)d_in[2];
  const float* Wq = (const float*)d_in[3];
  const float* bq = (const float*)d_in[4];
  const float* Wv = (const float*)d_in[5];
  const float* bv = (const float*)d_in[6];
  const float* Wp = (const float*)d_in[7];
  const float* bp = (const float*)d_in[8];
  float* out = (float*)d_out;

  const size_t elems = (size_t)MR * CD;      // 8388608
  const size_t welems = (size_t)CD * CD;     // 1048576

  if (ws_size >= 76ull*1024*1024) {
    uint16_t* xbf = (uint16_t*)d_ws;
    uint16_t* wqb = xbf + elems;             // wq|wk|wv contiguous = [3072][1024]
    uint16_t* wkb = wqb + welems;
    uint16_t* wvb = wkb + welems;
    uint16_t* wpb = wvb + welems;
    uint16_t* q_ws = wpb + welems;
    uint16_t* k_ws = q_ws + elems;
    uint16_t* v_ws = k_ws + elems;
    uint16_t* y_ws = xbf;                    // alias: x dead after QKV GEMM

    cvt5<<<6144, 256, 0, stream>>>(x, Wq, Wk, Wv, Wp, xbf, wqb, wkb, wvb, wpb);
    gemm_qkv8m<<<768, 512, 0, stream>>>(xbf, wqb, bq, bk, bv, q_ws, k_ws, v_ws);
    attn128s<<<512, 256, 0, stream>>>(q_ws, k_ws, v_ws, y_ws);
    gemm_proj8m<<<256, 512, 0, stream>>>(y_ws, wpb, bp, out);
  } else {
    uint16_t* q_ws = (uint16_t*)d_ws;
    uint16_t* k_ws = q_ws + elems;
    uint16_t* v_ws = k_ws + elems;
    uint16_t* y_ws = v_ws + elems;
    dim3 gg(CD/128, MR/128);
    gemm128o<0><<<gg, 256, 0, stream>>>(x, Wq, bq, q_ws, QSCALE);
    gemm128o<0><<<gg, 256, 0, stream>>>(x, Wk, bk, k_ws, 1.0f);
    gemm128o<2><<<gg, 256, 0, stream>>>(x, Wv, bv, v_ws, 1.0f);
    attn128s<<<512, 256, 0, stream>>>(q_ws, k_ws, v_ws, y_ws);
    gemm128o<1><<<gg, 256, 0, stream>>>(y_ws, Wp, bp, out, 1.0f);
  }
}